// Round 3
// baseline (25.689 us; speedup 1.0000x reference)
//
#include <hip/hip_runtime.h>

#define B_ 4
#define N_ 256
#define T_ 16
#define F_ 128
#define H_ 256
#define BN_ (B_ * N_)  // 1024

// ---------------------------------------------------------------------------
// lp_prep: blocks 0..127  : hbar[bn][f] = mean_t nodefeat[bn][t][f]
//          blocks 128..143: W1T[k][h] = W1[h][k]   (256x256 LDS-tiled transpose)
// ---------------------------------------------------------------------------
__global__ __launch_bounds__(1024) void lp_prep(const float* __restrict__ nf,
                                                const float* __restrict__ W1,
                                                float* __restrict__ hbar,
                                                float* __restrict__ W1T) {
    __shared__ float sT[64][65];
    const int tid = threadIdx.x;
    if (blockIdx.x < 128) {
        const int idx = blockIdx.x * 1024 + tid;   // bn*128 + f
        const int bn  = idx >> 7;
        const int f   = idx & 127;
        const float* src = nf + (size_t)bn * (T_ * F_) + f;
        float s = 0.f;
#pragma unroll
        for (int t = 0; t < T_; ++t) s += src[t * F_];
        hbar[idx] = s * (1.0f / 16.0f);
    } else {
        const int t  = blockIdx.x - 128;  // 0..15
        const int y0 = (t >> 2) * 64;     // h-tile base
        const int x0 = (t & 3) * 64;      // k-tile base
        const int ty = tid >> 6;          // 0..15
        const int tx = tid & 63;
#pragma unroll
        for (int r = 0; r < 4; ++r)
            sT[r * 16 + ty][tx] = W1[(size_t)(y0 + r * 16 + ty) * 256 + (x0 + tx)];
        __syncthreads();
#pragma unroll
        for (int r = 0; r < 4; ++r)
            W1T[(size_t)(x0 + r * 16 + ty) * 256 + (y0 + tx)] = sT[tx][r * 16 + ty];
    }
}

// ---------------------------------------------------------------------------
// lp_gemm: block = (8-node tile, h-half), 512 threads = (kq in 0..3, hl in 0..127).
//   acca[n] = sum_k hbar[bn0+n][k] * W1[h][k]      (k restricted to kq chunk)
//   accc[n] = sum_k hbar[bn0+n][k] * W1[h][F+k]
// W1T loads lane-coalesced (lanes = consecutive h); hbar via wave-uniform
// s_load_dwordx4 (scalar pipe, K$). LDS only for the final kq-reduction.
// Outputs: aT[tile4][h][4] (b1 folded), cT[b][h][N].
// ---------------------------------------------------------------------------
__global__ __launch_bounds__(512) void lp_gemm(const float* __restrict__ hbar,
                                               const float* __restrict__ W1T,
                                               const float* __restrict__ b1,
                                               float* __restrict__ aT,
                                               float* __restrict__ cT) {
    __shared__ float red[16][4][128];  // [val][kq][hl] = 32 KB

    const int tile8 = blockIdx.x >> 1;        // 0..127 -> 8 nodes
    const int h0    = (blockIdx.x & 1) * 128; // h half
    const int bn0   = tile8 * 8;
    const int b     = bn0 >> 8;
    const int tid   = threadIdx.x;
    const int kq    = __builtin_amdgcn_readfirstlane(tid >> 7);  // 0..3, wave-uniform
    const int hl    = tid & 127;
    const int h     = h0 + hl;

    const float* wA = W1T + (size_t)(kq * 32) * H_ + h;
    const float* wC = W1T + (size_t)(F_ + kq * 32) * H_ + h;
    const float* hb = hbar + (size_t)bn0 * F_ + kq * 32;  // wave-uniform base

    float acca[8] = {0.f, 0.f, 0.f, 0.f, 0.f, 0.f, 0.f, 0.f};
    float accc[8] = {0.f, 0.f, 0.f, 0.f, 0.f, 0.f, 0.f, 0.f};

#pragma unroll 4
    for (int kk = 0; kk < 32; ++kk) {
        const float wa = wA[(size_t)kk * H_];   // coalesced over lanes
        const float wc = wC[(size_t)kk * H_];
#pragma unroll
        for (int n = 0; n < 8; ++n) {
            const float hv = hb[n * F_ + kk];   // uniform -> s_load
            acca[n] = fmaf(hv, wa, acca[n]);
            accc[n] = fmaf(hv, wc, accc[n]);
        }
    }

    // reduce the 4 kq partials through LDS (conflict-free: lanes = hl)
#pragma unroll
    for (int n = 0; n < 8; ++n) {
        red[n][kq][hl]     = acca[n];
        red[8 + n][kq][hl] = accc[n];
    }
    __syncthreads();

    const int rv = tid >> 7;  // 0..3, each thread finishes 4 of the 16 values
#pragma unroll
    for (int i = 0; i < 4; ++i) {
        const int v = rv * 4 + i;  // 0..15
        const float s = (red[v][0][hl] + red[v][1][hl]) + (red[v][2][hl] + red[v][3][hl]);
        if (v < 8) {
            const int bn = bn0 + v;
            aT[((size_t)(bn >> 2) * H_ + h) * 4 + (bn & 3)] = s + b1[h];
        } else {
            const int n = v - 8;
            cT[((size_t)b * H_ + h) * N_ + ((bn0 & 255) + n)] = s;
        }
    }
}

// ---------------------------------------------------------------------------
// lp_k2: block = (b, 4-row i-tile), 1024 threads = (hq in 0..3, j in 0..255).
//   logits[b][i][j] = sum_h relu(aT[tile][h][i] + cT[b][h][j]) * W2[h] + b2
// a-tile + W2 via wave-uniform s_load (scalar pipe); cj coalesced vector load
// from L2-resident cT. No LDS in the hot loop; one LDS pass for hq-reduction.
// ---------------------------------------------------------------------------
__global__ __launch_bounds__(1024) void lp_k2(const float* __restrict__ aT,
                                              const float* __restrict__ cT,
                                              const float* __restrict__ W2,
                                              const float* __restrict__ b2,
                                              float* __restrict__ out) {
    __shared__ float pr[4][4][256];  // [row][hq][j] = 16 KB

    const int tile = blockIdx.x;  // 0..255
    const int bn0  = tile * 4;
    const int b    = bn0 >> 8;
    const int i0   = bn0 & 255;
    const int tid  = threadIdx.x;
    const int hq   = __builtin_amdgcn_readfirstlane(tid >> 8);  // 0..3
    const int j    = tid & 255;

    const float* crow = cT + (size_t)b * (H_ * N_) + j;
    const float* arow = aT + (size_t)tile * (H_ * 4);  // [h][4], uniform base
    const int h0 = hq * 64;

    float acc0 = 0.f, acc1 = 0.f, acc2 = 0.f, acc3 = 0.f;

#pragma unroll 8
    for (int hh = 0; hh < 64; ++hh) {
        const int h = h0 + hh;
        const float cj = crow[(size_t)h * N_];             // coalesced over j
        const float w  = W2[h];                            // uniform -> s_load
        const float4 av = *(const float4*)(arow + h * 4);  // uniform -> s_load_dwordx4
        float x;
        x = av.x + cj; acc0 = fmaf(fmaxf(x, 0.f), w, acc0);
        x = av.y + cj; acc1 = fmaf(fmaxf(x, 0.f), w, acc1);
        x = av.z + cj; acc2 = fmaf(fmaxf(x, 0.f), w, acc2);
        x = av.w + cj; acc3 = fmaf(fmaxf(x, 0.f), w, acc3);
    }

    pr[0][hq][j] = acc0;
    pr[1][hq][j] = acc1;
    pr[2][hq][j] = acc2;
    pr[3][hq][j] = acc3;
    __syncthreads();

    const int r  = tid >> 8;
    const int jj = tid & 255;
    const float s = (pr[r][0][jj] + pr[r][1][jj]) + (pr[r][2][jj] + pr[r][3][jj]);
    out[((size_t)b * N_ + (i0 + r)) * N_ + jj] = s + b2[0];
}

extern "C" void kernel_launch(void* const* d_in, const int* in_sizes, int n_in,
                              void* d_out, int out_size, void* d_ws, size_t ws_size,
                              hipStream_t stream) {
    const float* nodefeat = (const float*)d_in[0];  // [B,N,T,F]
    const float* W1       = (const float*)d_in[1];  // [H, 2F]
    const float* b1       = (const float*)d_in[2];  // [H]
    const float* W2       = (const float*)d_in[3];  // [1, H]
    const float* b2       = (const float*)d_in[4];  // [1]
    float* out = (float*)d_out;                     // [B,N,N]

    float* hbar = (float*)d_ws;                     // [1024][128]      = 512 KB
    float* W1T  = hbar + (size_t)BN_ * F_;          // [256][256]       = 256 KB
    float* aT   = W1T + 256 * 256;                  // [256 tiles][H][4] = 1 MB
    float* cT   = aT + (size_t)256 * H_ * 4;        // [B][H][N]         = 1 MB

    lp_prep<<<144, 1024, 0, stream>>>(nodefeat, W1, hbar, W1T);
    lp_gemm<<<256, 512, 0, stream>>>(hbar, W1T, b1, aT, cT);
    lp_k2<<<256, 1024, 0, stream>>>(aT, cT, W2, b2, out);
}